// Round 1
// baseline (260.455 us; speedup 1.0000x reference)
//
#include <hip/hip_runtime.h>

// CubicalModel: Xp = (I @ p).reshape(28,28); dgm1 = Xp[inds1[:,0], inds1[:,1]]
// Only 200 row-dot-products are needed (~40 MB HBM). Memory floor ~6.5 us.
//
// R3: FUSE to a single launch. One block (1024 threads) per output row:
//  - full 50000-elem dot per block, 12 float4 loads/thread, 4-way unrolled
//    independent accumulators for MLP/ILP
//  - wave shuffle reduce -> 16-entry LDS -> wave-0 reduce -> direct store
//  - removes reduce_partials node, partials HBM round-trip, and the 8x
//    redundant p-chunk streams of the SPLIT=8 version.

#define P_DIM 50000
#define NV    (P_DIM / 4)      // 12500 float4 per row
#define NGATH 100              // gathered elements per diagram
#define NOUT  200              // total outputs
#define BLOCK 1024

__global__ __launch_bounds__(BLOCK) void gather_dot_fused(
    const float* __restrict__ p,
    const float* __restrict__ I,
    const float* __restrict__ J,
    const int*   __restrict__ inds1,
    const int*   __restrict__ inds2,
    float*       __restrict__ out)
{
    const int o = blockIdx.x;       // 0 .. NOUT-1

    const float* mat;
    const int*   ind;
    int k;
    if (o < NGATH) { mat = I; ind = inds1; k = o; }
    else           { mat = J; ind = inds2; k = o - NGATH; }

    const int r = ind[2 * k];
    const int c = ind[2 * k + 1];
    const size_t flat = (size_t)(r * 28 + c);   // row of the 784 x 50000 matrix

    const float4* __restrict__ row = (const float4*)(mat + flat * (size_t)P_DIM);
    const float4* __restrict__ p4  = (const float4*)p;

    // 12500 float4: 3 main iterations of 4 loads each cover [0, 12288),
    // tail covers [12288, 12500).
    float s0 = 0.f, s1 = 0.f, s2 = 0.f, s3 = 0.f;
    int i = (int)threadIdx.x;
    for (; i + 3 * BLOCK < NV; i += 4 * BLOCK) {
        float4 a0 = row[i];             float4 b0 = p4[i];
        float4 a1 = row[i + BLOCK];     float4 b1 = p4[i + BLOCK];
        float4 a2 = row[i + 2 * BLOCK]; float4 b2 = p4[i + 2 * BLOCK];
        float4 a3 = row[i + 3 * BLOCK]; float4 b3 = p4[i + 3 * BLOCK];
        s0 += a0.x * b0.x + a0.y * b0.y + a0.z * b0.z + a0.w * b0.w;
        s1 += a1.x * b1.x + a1.y * b1.y + a1.z * b1.z + a1.w * b1.w;
        s2 += a2.x * b2.x + a2.y * b2.y + a2.z * b2.z + a2.w * b2.w;
        s3 += a3.x * b3.x + a3.y * b3.y + a3.z * b3.z + a3.w * b3.w;
    }
    for (; i < NV; i += BLOCK) {
        float4 a = row[i];
        float4 b = p4[i];
        s0 += a.x * b.x + a.y * b.y + a.z * b.z + a.w * b.w;
    }
    float sum = (s0 + s1) + (s2 + s3);

    // wave(64) shuffle reduction
    #pragma unroll
    for (int off = 32; off > 0; off >>= 1)
        sum += __shfl_down(sum, off, 64);

    __shared__ float smem[BLOCK / 64];   // 16 waves
    const int lane = threadIdx.x & 63;
    const int wave = threadIdx.x >> 6;
    if (lane == 0) smem[wave] = sum;
    __syncthreads();

    if (threadIdx.x < 64) {
        float v = (threadIdx.x < BLOCK / 64) ? smem[threadIdx.x] : 0.f;
        #pragma unroll
        for (int off = 8; off > 0; off >>= 1)
            v += __shfl_down(v, off, 64);
        if (threadIdx.x == 0) out[o] = v;
    }
}

extern "C" void kernel_launch(void* const* d_in, const int* in_sizes, int n_in,
                              void* d_out, int out_size, void* d_ws, size_t ws_size,
                              hipStream_t stream) {
    const float* p     = (const float*)d_in[0];
    const float* I     = (const float*)d_in[1];
    const float* J     = (const float*)d_in[2];
    const int*   inds1 = (const int*)d_in[3];
    const int*   inds2 = (const int*)d_in[4];
    float* out = (float*)d_out;

    gather_dot_fused<<<NOUT, BLOCK, 0, stream>>>(p, I, J, inds1, inds2, out);
}